// Round 10
// baseline (45.084 us; speedup 1.0000x reference)
//
#include <hip/hip_runtime.h>

// PatchManifoldLossPre: resize (8,19,512,512) -> (8,19,48,48) with jax.image.resize
// bilinear (antialias=True, triangle kernel, half-pixel centers), split into 4x4
// patches of 12x12, P[16, 21888], value = mean(weights * pairwise-MSD(P)).
// pairwise-MSD via Gram: map[a,b] = (G[aa]+G[bb]-2G[ab])/N; value linear in G.
//
// Round-10: ONE compute kernel. Block = (bc, within-patch y): produces the four
// output rows {y, y+12, y+24, y+36} (all 4 patch row-blocks at one y). Its 4x48
// gather tile holds all 16 patch values for its 12 (y,x) positions -> complete
// LOCAL 16x16 partial Gram -> local weight reduction -> one atomicAdd(out).
// No smallimg, no second dispatch, no cross-block dependency. Per-thread shape
// identical to measured-best r5: 1 output row-slice, 22 independent coalesced
// float4 loads, constexpr weight tables, swizzled-LDS horizontal gather.
// 1824 blocks (= 8*228, XCD-chunked) x 512 threads.

#define HIN 512
#define WOUT 48
#define NTAP 22
#define NBC 152              // 8*19
#define NBLK (NBC * 12)      // 1824 = 8 * 228
#define TSTRIDE 580          // swizzled LDS row stride in floats
#define KS (512.0 / 48.0)

// Compile-time triangle-kernel resize weights matching jax.image.resize
// (method="bilinear", antialias=True): sample s=(i+0.5)*KS-0.5, kernel scale KS,
// normalized over valid taps. Window clamped into [0, HIN-NTAP].
struct WTab {
  float hw[NTAP][WOUT];
  int hst[WOUT];
  constexpr WTab() : hw{}, hst{} {
    for (int i = 0; i < WOUT; ++i) {
      double s = (i + 0.5) * KS - 0.5;
      double v = s - KS;
      long long tt = (long long)v;                      // trunc toward zero
      int stc = (int)((v > (double)tt) ? tt + 1 : tt);  // ceil(v)
      if (stc < 0) stc = 0;
      if (stc > HIN - NTAP) stc = HIN - NTAP;
      double wr[NTAP] = {};
      double sum = 0.0;
      for (int k = 0; k < NTAP; ++k) {
        int j = stc + k;
        double d = s - (double)j;
        if (d < 0) d = -d;
        double wv = 1.0 - d * (1.0 / KS);
        if (wv < 0.0) wv = 0.0;
        if (j >= HIN) wv = 0.0;  // j<0 impossible after clamp
        wr[k] = wv;
        sum += wv;
      }
      for (int k = 0; k < NTAP; ++k) hw[k][i] = (float)(wr[k] / sum);
      hst[i] = stc;
    }
  }
};
__constant__ WTab WT{};

__global__ __launch_bounds__(512, 4) void k_fused(const float* __restrict__ pred,
                                                  const float* __restrict__ wts,
                                                  float* __restrict__ out) {
  __shared__ float tile[4][TSTRIDE];  // 9280 B, swizzled (c -> c + 4*(c>>5))
  __shared__ float img4[4][WOUT];     // 768 B: rows {y,y+12,y+24,y+36} x 48 cols
  __shared__ float Gs[256];
  __shared__ float partial[4];

  const int t = threadIdx.x;
  // XCD-chunked remap (bijective: 1824 = 8*228): round-robin XCD assignment gets
  // contiguous chunks; same-bc and y-adjacent blocks (11/22 tap-row overlap per
  // band) land on the same XCD's L2.
  const int wid = (blockIdx.x & 7) * (NBLK / 8) + (blockIdx.x >> 3);
  const int bc = wid / 12;
  const int y = wid - bc * 12;   // within-patch row 0..11

  // ---- Vertical pass: thread = (row-slot s=0..3, float4 column slice) ----
  const int s = t >> 7;               // wave-uniform (2 waves per slot)
  const int oy = s * 12 + y;          // output row: patch-block s at y
  const int x = (t & 127) << 2;       // 0..508
  const int base = WT.hst[oy];
  const float* p = pred + (size_t)bc * (HIN * HIN) + (size_t)base * HIN + x;
  float4 a4 = make_float4(0.f, 0.f, 0.f, 0.f);
#pragma unroll
  for (int k = 0; k < NTAP; ++k) {
    const float4 v = *reinterpret_cast<const float4*>(p + (size_t)k * HIN);
    const float wk = WT.hw[k][oy];    // wave-uniform constant read -> s_load
    a4.x = fmaf(wk, v.x, a4.x);
    a4.y = fmaf(wk, v.y, a4.y);
    a4.z = fmaf(wk, v.z, a4.z);
    a4.w = fmaf(wk, v.w, a4.w);
  }
  *reinterpret_cast<float4*>(&tile[s][x + ((x >> 5) << 2)]) = a4;
  __syncthreads();

  // ---- Horizontal gather (192 of 512 threads) -> img4 LDS ----
  if (t < 4 * WOUT) {
    const int r = t / WOUT;           // 0..3
    const int j = t - r * WOUT;
    const int stc = WT.hst[j];
    float acc = 0.f;
#pragma unroll
    for (int k = 0; k < NTAP; ++k) {
      const int cc = stc + k;
      acc = fmaf(WT.hw[k][j], tile[r][cc + ((cc >> 5) << 2)], acc);
    }
    img4[r][j] = acc;
  }
  __syncthreads();

  // ---- Local partial Gram over this block's 12 (y,x) positions ----
  // Patch a = n*4+m: value at position (y, x_in) is img4[n][m*12 + x_in].
  const int a = t >> 4;
  const int b = t & 15;
  if (t < 256) {
    const float* pa = &img4[a >> 2][(a & 3) * 12];
    const float* pb = &img4[b >> 2][(b & 3) * 12];
    float acc = 0.f;
#pragma unroll
    for (int q = 0; q < 3; ++q) {
      const float4 va = *reinterpret_cast<const float4*>(pa + q * 4);
      const float4 vb = *reinterpret_cast<const float4*>(pb + q * 4);
      acc += va.x * vb.x + va.y * vb.y + va.z * vb.z + va.w * vb.w;
    }
    Gs[t] = acc;
  }
  __syncthreads();

  // ---- Local weight reduction (value linear in per-block partial Gram) ----
  float v = 0.f;
  if (t < 256) v = wts[t] * (Gs[a * 17] + Gs[b * 17] - 2.0f * Gs[t]);
#pragma unroll
  for (int off = 32; off > 0; off >>= 1) v += __shfl_down(v, off, 64);
  if (t < 256 && (t & 63) == 0) partial[t >> 6] = v;
  __syncthreads();
  if (t == 0) {
    atomicAdd(out, (partial[0] + partial[1] + partial[2] + partial[3]) *
                       (float)(1.0 / (256.0 * 21888.0)));
  }
}

extern "C" void kernel_launch(void* const* d_in, const int* in_sizes, int n_in,
                              void* d_out, int out_size, void* d_ws, size_t ws_size,
                              hipStream_t stream) {
  const float* pred = (const float*)d_in[0];
  const float* wts = (const float*)d_in[1];
  float* out = (float*)d_out;

  hipMemsetAsync(out, 0, sizeof(float), stream);  // atomic accumulator init
  hipLaunchKernelGGL(k_fused, dim3(NBLK), dim3(512), 0, stream, pred, wts, out);
}

// Round 11
// 34.890 us; speedup vs baseline: 1.2922x; 1.2922x over previous
//
#include <hip/hip_runtime.h>

// PatchManifoldLossPre: resize (8,19,512,512) -> (8,19,48,48) with jax.image.resize
// bilinear (antialias=True, triangle kernel, half-pixel centers), split into 4x4
// patches of 12x12, P[16, 21888], value = mean(weights * pairwise-MSD(P)).
// pairwise-MSD via Gram: map[a,b] = (G[aa]+G[bb]-2G[ab])/N; value linear in G.
//
// Round-11 = round-9 restored (measured best: 34.9 us). Design-space summary:
//  - 3648 blocks x 256 thr, 1 output row per thread-slot, 22 independent
//    coalesced float4 loads: BEST. More blocks (r2), fatter threads (r4/r7),
//    512-thr fused blocks (r10), ticket-fused tails (r3) ALL regressed.
//  - constexpr weight tables (no per-block preamble), swizzled-LDS horizontal
//    gather (c -> c + 4*(c>>5): ~2-way conflicts = free).
//  - Tail: per-bc local Gram + local weight reduction (value linear in G),
//    ONE atomicAdd(out) per bc block; out zeroed by k_resize block 0.
// Budget: k_resize ~30 us (vs ~25 us composite L3/HBM floor), k_gram ~2.5,
// launch gap ~2.

#define HIN 512
#define WOUT 48
#define NTAP 22
#define NBC 152              // 8*19
#define NPAIR 24             // row-pairs per bc
#define NBLK (NBC * NPAIR)   // 3648 = 8 * 456
#define TSTRIDE 580          // swizzled LDS row stride in floats
#define GROUP 12             // patch size
#define KS (512.0 / 48.0)

// Compile-time triangle-kernel resize weights matching jax.image.resize
// (method="bilinear", antialias=True): sample s=(i+0.5)*KS-0.5, kernel scale KS,
// normalized over valid taps. Window clamped into [0, HIN-NTAP].
struct WTab {
  float hw[NTAP][WOUT];
  int hst[WOUT];
  constexpr WTab() : hw{}, hst{} {
    for (int i = 0; i < WOUT; ++i) {
      double s = (i + 0.5) * KS - 0.5;
      double v = s - KS;
      long long tt = (long long)v;                      // trunc toward zero
      int stc = (int)((v > (double)tt) ? tt + 1 : tt);  // ceil(v)
      if (stc < 0) stc = 0;
      if (stc > HIN - NTAP) stc = HIN - NTAP;
      double wr[NTAP] = {};
      double sum = 0.0;
      for (int k = 0; k < NTAP; ++k) {
        int j = stc + k;
        double d = s - (double)j;
        if (d < 0) d = -d;
        double wv = 1.0 - d * (1.0 / KS);
        if (wv < 0.0) wv = 0.0;
        if (j >= HIN) wv = 0.0;  // j<0 impossible after clamp
        wr[k] = wv;
        sum += wv;
      }
      for (int k = 0; k < NTAP; ++k) hw[k][i] = (float)(wr[k] / sum);
      hst[i] = stc;
    }
  }
};
__constant__ WTab WT{};

__global__ __launch_bounds__(256, 6) void k_resize(const float* __restrict__ pred,
                                                   float* __restrict__ smallimg,
                                                   float* __restrict__ out) {
  __shared__ float tile[2][TSTRIDE];  // 4640 B, swizzled (c -> c + 4*(c>>5))

  const int t = threadIdx.x;
  // XCD-chunked remap (bijective: 3648 = 8*456): round-robin XCD assignment gets
  // contiguous work chunks so row-adjacent pairs reuse that XCD's L2 tap rows.
  const int wid = (blockIdx.x & 7) * (NBLK / 8) + (blockIdx.x >> 3);
  const int bc = wid / NPAIR;
  const int pair = wid - bc * NPAIR;

  // Zero the output accumulator (poisoned by harness): visible to k_gram at the
  // kernel boundary on the same stream.
  if (blockIdx.x == 0 && t == 0) out[0] = 0.f;

  // ---- Vertical pass: thread = (output row slot, float4 column slice) ----
  const int slot = t >> 7;              // 0..1 (wave-uniform)
  const int oy = pair * 2 + slot;
  const int x = (t & 127) << 2;         // 0..508
  const int base = WT.hst[oy];
  const float* p = pred + (size_t)bc * (HIN * HIN) + (size_t)base * HIN + x;
  float4 a = make_float4(0.f, 0.f, 0.f, 0.f);
#pragma unroll
  for (int k = 0; k < NTAP; ++k) {
    const float4 v = *reinterpret_cast<const float4*>(p + (size_t)k * HIN);
    const float wk = WT.hw[k][oy];      // wave-uniform constant read -> s_load
    a.x = fmaf(wk, v.x, a.x);
    a.y = fmaf(wk, v.y, a.y);
    a.z = fmaf(wk, v.z, a.z);
    a.w = fmaf(wk, v.w, a.w);
  }
  *reinterpret_cast<float4*>(&tile[slot][x + ((x >> 5) << 2)]) = a;
  __syncthreads();

  // ---- Horizontal gather (96 of 256 threads) -> smallimg ----
  if (t < 2 * WOUT) {
    const int r = (t >= WOUT) ? 1 : 0;
    const int j = t - r * WOUT;
    const int stc = WT.hst[j];
    float acc = 0.f;
#pragma unroll
    for (int k = 0; k < NTAP; ++k) {
      const int cc = stc + k;
      acc = fmaf(WT.hw[k][j], tile[r][cc + ((cc >> 5) << 2)], acc);
    }
    smallimg[(size_t)bc * (WOUT * WOUT) + (pair * 2 + r) * WOUT + j] = acc;
  }
}

// One block per (b,c): stage 48x48 image in LDS; thread (a,b)=(tid>>4,tid&15)
// computes local Gram entry; block applies the weight reduction LOCALLY
// (value is linear in per-bc Gram) and atomicAdds one pre-scaled float to out.
__global__ __launch_bounds__(256) void k_gram(const float* __restrict__ smallimg,
                                              const float* __restrict__ wts,
                                              float* __restrict__ out) {
  __shared__ float img[WOUT * WOUT];
  __shared__ float Gs[256];
  __shared__ float partial[4];

  const int tid = threadIdx.x;
  const float* src = smallimg + (size_t)blockIdx.x * (WOUT * WOUT);
  for (int idx = tid; idx < (WOUT * WOUT) / 4; idx += 256) {
    *reinterpret_cast<float4*>(&img[idx * 4]) =
        *reinterpret_cast<const float4*>(src + idx * 4);
  }
  __syncthreads();
  const int a = tid >> 4;
  const int b = tid & 15;
  const float* pa = &img[((a >> 2) * GROUP) * WOUT + (a & 3) * GROUP];
  const float* pb = &img[((b >> 2) * GROUP) * WOUT + (b & 3) * GROUP];
  float acc = 0.f;
  for (int y = 0; y < GROUP; ++y) {
#pragma unroll
    for (int q = 0; q < 3; ++q) {
      const float4 va = *reinterpret_cast<const float4*>(pa + y * WOUT + q * 4);
      const float4 vb = *reinterpret_cast<const float4*>(pb + y * WOUT + q * 4);
      acc += va.x * vb.x + va.y * vb.y + va.z * vb.z + va.w * vb.w;
    }
  }
  Gs[tid] = acc;
  __syncthreads();

  float v = wts[tid] * (Gs[a * 17] + Gs[b * 17] - 2.0f * Gs[tid]);
#pragma unroll
  for (int off = 32; off > 0; off >>= 1) v += __shfl_down(v, off, 64);
  if ((tid & 63) == 0) partial[tid >> 6] = v;
  __syncthreads();
  if (tid == 0) {
    atomicAdd(out, (partial[0] + partial[1] + partial[2] + partial[3]) *
                       (float)(1.0 / (256.0 * 21888.0)));
  }
}

extern "C" void kernel_launch(void* const* d_in, const int* in_sizes, int n_in,
                              void* d_out, int out_size, void* d_ws, size_t ws_size,
                              hipStream_t stream) {
  const float* pred = (const float*)d_in[0];
  const float* wts = (const float*)d_in[1];
  float* out = (float*)d_out;
  float* smallimg = (float*)((char*)d_ws + 2048);  // 152*48*48 floats

  hipLaunchKernelGGL(k_resize, dim3(NBLK), dim3(256), 0, stream, pred, smallimg, out);
  hipLaunchKernelGGL(k_gram, dim3(NBC), dim3(256), 0, stream, smallimg, wts, out);
}